// Round 2
// baseline (1143.468 us; speedup 1.0000x reference)
//
#include <hip/hip_runtime.h>
#include <stdint.h>

#define TT 512
#define BB 32
#define EE 512
#define HH 2048

typedef __attribute__((ext_vector_type(8))) short short8;   // 8 x bf16 (4 VGPRs)
typedef __attribute__((ext_vector_type(4))) float f32x4;    // MFMA accumulator

static __device__ __forceinline__ unsigned short f2bf(float f) {
    union { float f; unsigned u; } v; v.f = f;
    unsigned u = v.u;
    unsigned r = u + 0x7FFFu + ((u >> 16) & 1u);   // round-to-nearest-even
    return (unsigned short)(r >> 16);
}

static __device__ __forceinline__ float fast_exp(float x) {
    return __builtin_amdgcn_exp2f(x * 1.44269504f);
}
static __device__ __forceinline__ float fast_rcp(float x) {
    return __builtin_amdgcn_rcpf(x);
}

// ---------------------------------------------------------------------------
// Pre-kernel: convert sent (T,B,E) fp32 and W (3H,E) fp32 to bf16 in ws.
// 8 elems/thread: 2x float4 loads + one 16B store (fully coalesced).
// nX divisible by 8, so no thread straddles the X/W boundary.
// ---------------------------------------------------------------------------
__global__ void convert_inputs(const float* __restrict__ X,
                               const float* __restrict__ W,
                               unsigned short* __restrict__ Xb,
                               unsigned short* __restrict__ Wb) {
    const int nX = TT * BB * EE;              // 8,388,608
    int i = (blockIdx.x * blockDim.x + threadIdx.x) * 8;
    const float* src;
    unsigned short* dst;
    int j;
    if (i < nX) { src = X; dst = Xb; j = i; }
    else        { src = W; dst = Wb; j = i - nX; }
    float4 v0 = *(const float4*)(src + j);
    float4 v1 = *(const float4*)(src + j + 4);
    union { short8 s; unsigned short u[8]; } o;
    o.u[0] = f2bf(v0.x); o.u[1] = f2bf(v0.y); o.u[2] = f2bf(v0.z); o.u[3] = f2bf(v0.w);
    o.u[4] = f2bf(v1.x); o.u[5] = f2bf(v1.y); o.u[6] = f2bf(v1.z); o.u[7] = f2bf(v1.w);
    *(short8*)(dst + j) = o.s;
}

// ---------------------------------------------------------------------------
// Fused QRNN kernel.
// Block = (batch b, 64 h-columns). 4 waves x 16 h each. Wave-resident W frags
// (PINNED in VGPRs via inline-asm liveness barrier — without it the compiler
// sinks the W loads into the chunk loop and the kernel becomes L2-BW-bound:
// 6.3 GB L2 reads = 183 us, measured R1).
// Per 16-t chunk: MFMA GEMM (z,f,o) -> activations -> in-register affine scan
// over t (shuffle-composed across quads) -> running max of o*c.
// ---------------------------------------------------------------------------
#define LDS_STRIDE 528   // shorts per LDS row: 512 + 16 pad (2-way bank alias = free)

__launch_bounds__(256, 2)
__global__ void qrnn_fused(const unsigned short* __restrict__ Xb, // bf16 (T,B,E)
                           const unsigned short* __restrict__ Wb, // bf16 (3H,E)
                           const float* __restrict__ bias,        // (3H)
                           float* __restrict__ out)               // (B,H) fp32
{
    __shared__ unsigned short lds[2][16 * LDS_STRIDE];

    const int tid  = threadIdx.x;
    const int wv   = tid >> 6;         // wave 0..3
    const int lane = tid & 63;
    const int q    = lane >> 4;        // quad 0..3
    const int c    = lane & 15;        // column within 16x16 tile
    const int b    = blockIdx.y;
    const int h    = blockIdx.x * 64 + wv * 16 + c;   // this lane's h column

    // ---- preload W fragments into VGPRs (3 planes x 16 k-steps) ----
    // B-frag layout for 16x16x32: lane holds n = lane&15 (= h), k = q*8 + j.
    short8 wz[16], wf[16], wo[16];
    {
        const unsigned short* wzr = Wb + (size_t)h * EE;
        const unsigned short* wfr = Wb + (size_t)(HH + h) * EE;
        const unsigned short* wor = Wb + (size_t)(2 * HH + h) * EE;
#pragma unroll
        for (int k = 0; k < 16; ++k) {
            int e0 = k * 32 + q * 8;
            wz[k] = *(const short8*)(wzr + e0);
            wf[k] = *(const short8*)(wfr + e0);
            wo[k] = *(const short8*)(wor + e0);
        }
    }
    // Liveness pin: makes the 192 W VGPRs opaque so the register allocator
    // cannot rematerialize/sink the loads into the chunk loop.
#pragma unroll
    for (int k = 0; k < 16; ++k) {
        asm volatile("" : "+v"(wz[k]), "+v"(wf[k]), "+v"(wo[k]));
    }

    const float bz = bias[h];
    const float bf_ = bias[HH + h];
    const float bo = bias[2 * HH + h];

    float carry = 0.0f;      // c_{t-1} entering this chunk (per column)
    float vmax  = -1e30f;    // running max of o*c

    // staging: 256 threads copy 16 rows x 512 bf16 (global, coalesced 16B) to LDS
    auto stage = [&](int ch, int buf) {
        const int row  = tid >> 4;      // 0..15
        const int blk0 = tid & 15;      // 16B block id
        const unsigned short* src = Xb + ((size_t)(ch * 16 + row) * BB + b) * EE;
        unsigned short* dst = &lds[buf][row * LDS_STRIDE];
#pragma unroll
        for (int i = 0; i < 4; ++i) {
            int blk = blk0 + 16 * i;
            *(short8*)(dst + blk * 8) = *(const short8*)(src + blk * 8);
        }
    };

    stage(0, 0);
    __syncthreads();

    for (int ch = 0; ch < TT / 16; ++ch) {
        const int buf = ch & 1;
        if (ch + 1 < TT / 16) stage(ch + 1, buf ^ 1);

        // ---- GEMM for this chunk: A = X[t,:], B = W rows; 3 planes ----
        // Bias folded into accumulator init (saves 12 VALU adds/chunk).
        f32x4 az = {bz, bz, bz, bz};
        f32x4 af = {bf_, bf_, bf_, bf_};
        f32x4 ao = {bo, bo, bo, bo};
        // A-frag layout: lane holds m = lane&15 (= t within chunk), k = q*8 + j
        const unsigned short* Abase = &lds[buf][c * LDS_STRIDE + q * 8];
        // unroll 4: caps transient A-frag VGPR pressure (full unroll would
        // hoist 16 ds_reads = +64 VGPR on top of 192 pinned -> spill)
#pragma unroll 4
        for (int k = 0; k < 16; ++k) {
            short8 a = *(const short8*)(Abase + k * 32);
            az = __builtin_amdgcn_mfma_f32_16x16x32_bf16(a, wz[k], az, 0, 0, 0);
            af = __builtin_amdgcn_mfma_f32_16x16x32_bf16(a, wf[k], af, 0, 0, 0);
            ao = __builtin_amdgcn_mfma_f32_16x16x32_bf16(a, wo[k], ao, 0, 0, 0);
        }

        // ---- activations: lane owns t = q*4 + r, column h ----
        // sigmoid(y) = rcp(1+exp(-y)); tanh(y) = 1 - 2*rcp(exp(2y)+1)
        // (v_rcp_f32/v_exp_f32; precise-div sequence is ~10 ops each)
        float aa[4], mm[4], oo[4];
#pragma unroll
        for (int r = 0; r < 4; ++r) {
            float e2 = fast_exp(2.0f * az[r]);
            float z  = 1.0f - 2.0f * fast_rcp(e2 + 1.0f);  // tanh
            float f  = fast_rcp(1.0f + fast_exp(-af[r]));  // sigmoid
            float o  = fast_rcp(1.0f + fast_exp(-ao[r]));  // sigmoid
            aa[r] = f * z;         // additive term
            mm[r] = 1.0f - f;      // multiplicative term
            oo[r] = o;
        }

        // ---- affine scan: compose lane's 4 steps, then scan across quads ----
        float A = aa[0], M = mm[0];
#pragma unroll
        for (int r = 1; r < 4; ++r) { A = aa[r] + mm[r] * A; M = mm[r] * M; }

        float Ap = __shfl_up(A, 16, 64), Mp = __shfl_up(M, 16, 64);
        if (q >= 1) { A = A + M * Ap; M = M * Mp; }
        Ap = __shfl_up(A, 32, 64); Mp = __shfl_up(M, 32, 64);
        if (q >= 2) { A = A + M * Ap; M = M * Mp; }
        // exclusive prefix for this lane's segment start
        float Ae = __shfl_up(A, 16, 64), Me = __shfl_up(M, 16, 64);
        if (q == 0) { Ae = 0.0f; Me = 1.0f; }
        float cc = Ae + Me * carry;

        // ---- replay the 4 steps exactly; track max(o*c) ----
#pragma unroll
        for (int r = 0; r < 4; ++r) {
            cc = aa[r] + mm[r] * cc;
            vmax = fmaxf(vmax, oo[r] * cc);
        }

        // carry out = chunk-end c (q==3 lane's inclusive transform on carry)
        float cend = A + M * carry;
        carry = __shfl(cend, 48 + c, 64);

        __syncthreads();   // staging of ch+1 done AND buf safe to overwrite
    }

    // reduce max across the 4 quads of each column
    vmax = fmaxf(vmax, __shfl_xor(vmax, 16, 64));
    vmax = fmaxf(vmax, __shfl_xor(vmax, 32, 64));
    if (q == 0) out[(size_t)b * HH + h] = vmax;
}

// ---------------------------------------------------------------------------
extern "C" void kernel_launch(void* const* d_in, const int* in_sizes, int n_in,
                              void* d_out, int out_size, void* d_ws, size_t ws_size,
                              hipStream_t stream) {
    const float* sent = (const float*)d_in[0];
    // d_in[1] = lengths (unused by the math)
    const float* W    = (const float*)d_in[2];
    const float* bias = (const float*)d_in[3];
    float* out        = (float*)d_out;

    const int nX = TT * BB * EE;        // 8,388,608
    const int nW = 3 * HH * EE;         // 3,145,728
    unsigned short* Xb = (unsigned short*)d_ws;
    unsigned short* Wb = Xb + nX;       // 16 MiB offset, 16B-aligned

    int totalVec = (nX + nW) / 8;       // 1,441,792 threads, exact cover
    convert_inputs<<<totalVec / 256, 256, 0, stream>>>(sent, W, Xb, Wb);

    dim3 grid(HH / 64, BB);             // (32, 32) = 1024 blocks
    qrnn_fused<<<grid, 256, 0, stream>>>(Xb, Wb, bias, out);
}

// Round 3
// 226.879 us; speedup vs baseline: 5.0400x; 5.0400x over previous
//
#include <hip/hip_runtime.h>
#include <stdint.h>

#define TT 512
#define BB 32
#define EE 512
#define HH 2048

typedef __attribute__((ext_vector_type(8))) short short8;   // 8 x bf16 (4 VGPRs)
typedef __attribute__((ext_vector_type(4))) float f32x4;    // MFMA accumulator

static __device__ __forceinline__ unsigned short f2bf(float f) {
    union { float f; unsigned u; } v; v.f = f;
    unsigned u = v.u;
    unsigned r = u + 0x7FFFu + ((u >> 16) & 1u);   // round-to-nearest-even
    return (unsigned short)(r >> 16);
}

static __device__ __forceinline__ float fast_exp(float x) {
    return __builtin_amdgcn_exp2f(x * 1.44269504f);
}
static __device__ __forceinline__ float fast_rcp(float x) {
    return __builtin_amdgcn_rcpf(x);
}

// ---------------------------------------------------------------------------
// Pre-kernel: convert sent (T,B,E) fp32 and W (3H,E) fp32 to bf16 in ws.
// (R2 measured ~12 us — at the HBM roofline for 92 MB of traffic.)
// ---------------------------------------------------------------------------
__global__ void convert_inputs(const float* __restrict__ X,
                               const float* __restrict__ W,
                               unsigned short* __restrict__ Xb,
                               unsigned short* __restrict__ Wb) {
    const int nX = TT * BB * EE;              // 8,388,608 (divisible by 8)
    int i = (blockIdx.x * blockDim.x + threadIdx.x) * 8;
    const float* src;
    unsigned short* dst;
    int j;
    if (i < nX) { src = X; dst = Xb; j = i; }
    else        { src = W; dst = Wb; j = i - nX; }
    float4 v0 = *(const float4*)(src + j);
    float4 v1 = *(const float4*)(src + j + 4);
    union { short8 s; unsigned short u[8]; } o;
    o.u[0] = f2bf(v0.x); o.u[1] = f2bf(v0.y); o.u[2] = f2bf(v0.z); o.u[3] = f2bf(v0.w);
    o.u[4] = f2bf(v1.x); o.u[5] = f2bf(v1.y); o.u[6] = f2bf(v1.z); o.u[7] = f2bf(v1.w);
    *(short8*)(dst + j) = o.s;
}

// ---------------------------------------------------------------------------
// Fused QRNN kernel, K-SPLIT variant.
// Block = (batch b, 32 h-cols), 4 waves = 2 h-tiles x 2 k-halves.
// Each wave pins only 96 W VGPRs (3 planes x 8 k-steps of its 256-wide K
// half) — R2 showed 192 pinned spills to scratch (104 VGPR + 3.3 GB scratch
// reloads); 96 leaves ~75 regs of slack under the 256 budget.
// Per 16-t chunk: partial MFMA GEMM -> LDS partial-sum exchange (s=1 -> s=0)
// -> s=0 wave does activations + in-register affine scan + running max.
// ---------------------------------------------------------------------------
#define LDS_STRIDE 528   // shorts per row; measured 0 LDS bank conflicts (R1/R2)

__launch_bounds__(256, 2)
__global__ void qrnn_fused(const unsigned short* __restrict__ Xb, // bf16 (T,B,E)
                           const unsigned short* __restrict__ Wb, // bf16 (3H,E)
                           const float* __restrict__ bias,        // (3H)
                           float* __restrict__ out)               // (B,H) fp32
{
    __shared__ unsigned short lds[2][16 * LDS_STRIDE];   // X chunk, double-buffered
    __shared__ float exch[2][64][12];                    // per h-tile partial sums

    const int tid  = threadIdx.x;
    const int wv   = tid >> 6;         // wave 0..3
    const int lane = tid & 63;
    const int q    = lane >> 4;        // quad 0..3
    const int c    = lane & 15;        // column within 16x16 tile
    const int hi   = wv >> 1;          // h-tile 0..1
    const int s    = wv & 1;           // k-half 0..1
    const int b    = blockIdx.y;
    const int h    = blockIdx.x * 32 + hi * 16 + c;   // this lane's h column

    // ---- preload W fragments (this wave's K half) into VGPRs ----
    // B-frag layout for 16x16x32: lane holds n = lane&15 (= h), k = q*8 + j.
    short8 wz[8], wf[8], wo[8];
    {
        const unsigned short* wzr = Wb + (size_t)h * EE            + s * 256;
        const unsigned short* wfr = Wb + (size_t)(HH + h) * EE     + s * 256;
        const unsigned short* wor = Wb + (size_t)(2 * HH + h) * EE + s * 256;
#pragma unroll
        for (int k = 0; k < 8; ++k) {
            int e0 = k * 32 + q * 8;
            wz[k] = *(const short8*)(wzr + e0);
            wf[k] = *(const short8*)(wfr + e0);
            wo[k] = *(const short8*)(wor + e0);
        }
    }
    // Liveness pin: prevents sinking the W loads into the chunk loop
    // (R1 pathology: sunk loads = 6.3 GB L2 traffic = 183 us).
#pragma unroll
    for (int k = 0; k < 8; ++k) {
        asm volatile("" : "+v"(wz[k]), "+v"(wf[k]), "+v"(wo[k]));
    }

    // bias folded into acc init; only the s==0 (summing) wave carries it
    const float b0 = (s == 0) ? bias[h]          : 0.0f;
    const float b1 = (s == 0) ? bias[HH + h]     : 0.0f;
    const float b2 = (s == 0) ? bias[2 * HH + h] : 0.0f;

    float carry = 0.0f;      // c_{t-1} entering this chunk (per column)
    float vmax  = -1e30f;    // running max of o*c

    // staging: 256 threads copy 16 rows x 512 bf16 (coalesced 16B) into LDS
    auto stage = [&](int ch, int buf) {
        const int row  = tid >> 4;      // 0..15
        const int blk0 = tid & 15;      // 16B block id
        const unsigned short* src = Xb + ((size_t)(ch * 16 + row) * BB + b) * EE;
        unsigned short* dst = &lds[buf][row * LDS_STRIDE];
#pragma unroll
        for (int i = 0; i < 4; ++i) {
            int blk = blk0 + 16 * i;
            *(short8*)(dst + blk * 8) = *(const short8*)(src + blk * 8);
        }
    };

    stage(0, 0);
    __syncthreads();

    for (int ch = 0; ch < TT / 16; ++ch) {
        const int buf = ch & 1;
        // issue next chunk's staging loads early so they fly under the MFMAs
        if (ch + 1 < TT / 16) stage(ch + 1, buf ^ 1);

        // ---- partial GEMM over this wave's K half ----
        f32x4 az = {b0, b0, b0, b0};
        f32x4 af = {b1, b1, b1, b1};
        f32x4 ao = {b2, b2, b2, b2};
        // A-frag: lane holds m = lane&15 (= t within chunk), k = q*8 + j
        const unsigned short* Abase = &lds[buf][c * LDS_STRIDE + s * 256 + q * 8];
#pragma unroll
        for (int k = 0; k < 8; ++k) {
            short8 a = *(const short8*)(Abase + k * 32);
            az = __builtin_amdgcn_mfma_f32_16x16x32_bf16(a, wz[k], az, 0, 0, 0);
            af = __builtin_amdgcn_mfma_f32_16x16x32_bf16(a, wf[k], af, 0, 0, 0);
            ao = __builtin_amdgcn_mfma_f32_16x16x32_bf16(a, wo[k], ao, 0, 0, 0);
        }

        // ---- partial-sum exchange: s=1 writes, s=0 sums ----
        if (s == 1) {
            float* e = &exch[hi][lane][0];
            *(f32x4*)(e)     = az;
            *(f32x4*)(e + 4) = af;
            *(f32x4*)(e + 8) = ao;
        }
        __syncthreads();

        if (s == 0) {
            const float* e = &exch[hi][lane][0];
            f32x4 pz = *(const f32x4*)(e);
            f32x4 pf = *(const f32x4*)(e + 4);
            f32x4 po = *(const f32x4*)(e + 8);
            az = az + pz; af = af + pf; ao = ao + po;

            // ---- activations: lane owns t = q*4 + r, column h ----
            float aa[4], mm[4], oo[4];
#pragma unroll
            for (int r = 0; r < 4; ++r) {
                float e2 = fast_exp(2.0f * az[r]);
                float z  = 1.0f - 2.0f * fast_rcp(e2 + 1.0f);  // tanh
                float f  = fast_rcp(1.0f + fast_exp(-af[r]));  // sigmoid
                float o  = fast_rcp(1.0f + fast_exp(-ao[r]));  // sigmoid
                aa[r] = f * z;
                mm[r] = 1.0f - f;
                oo[r] = o;
            }

            // ---- affine scan: compose 4 steps, scan across quads ----
            float A = aa[0], M = mm[0];
#pragma unroll
            for (int r = 1; r < 4; ++r) { A = aa[r] + mm[r] * A; M = mm[r] * M; }

            float Ap = __shfl_up(A, 16, 64), Mp = __shfl_up(M, 16, 64);
            if (q >= 1) { A = A + M * Ap; M = M * Mp; }
            Ap = __shfl_up(A, 32, 64); Mp = __shfl_up(M, 32, 64);
            if (q >= 2) { A = A + M * Ap; M = M * Mp; }
            float Ae = __shfl_up(A, 16, 64), Me = __shfl_up(M, 16, 64);
            if (q == 0) { Ae = 0.0f; Me = 1.0f; }
            float cc = Ae + Me * carry;

#pragma unroll
            for (int r = 0; r < 4; ++r) {
                cc = aa[r] + mm[r] * cc;
                vmax = fmaxf(vmax, oo[r] * cc);
            }

            float cend = A + M * carry;
            carry = __shfl(cend, 48 + c, 64);
        }

        __syncthreads();   // staging visible + exch reads done before next write
    }

    if (s == 0) {
        vmax = fmaxf(vmax, __shfl_xor(vmax, 16, 64));
        vmax = fmaxf(vmax, __shfl_xor(vmax, 32, 64));
        if (q == 0) out[(size_t)b * HH + h] = vmax;
    }
}

// ---------------------------------------------------------------------------
extern "C" void kernel_launch(void* const* d_in, const int* in_sizes, int n_in,
                              void* d_out, int out_size, void* d_ws, size_t ws_size,
                              hipStream_t stream) {
    const float* sent = (const float*)d_in[0];
    // d_in[1] = lengths (unused by the math)
    const float* W    = (const float*)d_in[2];
    const float* bias = (const float*)d_in[3];
    float* out        = (float*)d_out;

    const int nX = TT * BB * EE;        // 8,388,608
    const int nW = 3 * HH * EE;         // 3,145,728
    unsigned short* Xb = (unsigned short*)d_ws;
    unsigned short* Wb = Xb + nX;       // 16 MiB offset, 16B-aligned

    int totalVec = (nX + nW) / 8;       // 1,441,792 threads, exact cover
    convert_inputs<<<totalVec / 256, 256, 0, stream>>>(sent, W, Xb, Wb);

    dim3 grid(HH / 32, BB);             // (64, 32) = 2048 blocks
    qrnn_fused<<<grid, 256, 0, stream>>>(Xb, Wb, bias, out);
}